// Round 1
// baseline (3264.125 us; speedup 1.0000x reference)
//
#include <hip/hip_runtime.h>
#include <stdint.h>

// Problem constants (from reference)
#define N_ROWS 32768
#define KCODES 8192
#define DIM    512
#define DECAYF 0.8f
#define OMDF   0.2f      // 1 - DECAY
#define EPSF   1e-5f

// d_out layout (float32, reference return order, flat-concatenated)
#define OUT_QUANT 0
#define OUT_IND   (N_ROWS * DIM)                 // 16777216
#define OUT_CSN   (OUT_IND + N_ROWS)             // 16809984
#define OUT_AVG   (OUT_CSN + KCODES)             // 16818176
#define OUT_NORM  (OUT_AVG + KCODES * DIM)       // 21012480

// ws layout:
// [0, 262144)            u64 best[N_ROWS]   (packed argmax)
// [262144, 294912)       f32 norm2[KCODES]
// [294912, 294916)       f32 S (sum of cluster_size_new)
// [294916, 327684)       f32 inv_cs[KCODES]

__device__ __forceinline__ unsigned int enc_f(float v) {
    unsigned int b = __float_as_uint(v);
    return (b & 0x80000000u) ? ~b : (b | 0x80000000u);  // order-preserving for max
}

// ---- init: avg_new = DECAY*embed_avg ; csn = DECAY*cs ; best = 0 ----
__global__ void init_k(const float* __restrict__ cs,
                       const float* __restrict__ eavg,
                       float* __restrict__ out,
                       unsigned long long* __restrict__ best) {
    int i = blockIdx.x * blockDim.x + threadIdx.x;
    int stride = gridDim.x * blockDim.x;
    for (int idx = i; idx < KCODES * DIM; idx += stride) {
        out[OUT_AVG + idx] = DECAYF * eavg[idx];
        if (idx < KCODES) out[OUT_CSN + idx] = DECAYF * cs[idx];
        if (idx < N_ROWS) best[idx] = 0ull;
    }
}

// ---- per-code squared norm: one wave per code ----
__global__ void norms_k(const float* __restrict__ embed, float* __restrict__ norm2) {
    int gt   = blockIdx.x * blockDim.x + threadIdx.x;
    int wave = gt >> 6;
    int lane = threadIdx.x & 63;
    if (wave >= KCODES) return;
    const float4* row = (const float4*)(embed + wave * DIM);
    float s = 0.f;
    #pragma unroll
    for (int j = 0; j < 2; ++j) {
        float4 v = row[lane * 2 + j];
        s += v.x * v.x + v.y * v.y + v.z * v.z + v.w * v.w;
    }
    #pragma unroll
    for (int off = 32; off; off >>= 1) s += __shfl_down(s, off);
    if (lane == 0) norm2[wave] = s;
}

// ---- K1: fp32 distance GEMM + fused per-row argmax ----
// BM=BN=128, BK=16, 256 threads, 8x8 micro-tile per thread.
#define BM 128
#define BN 128
#define BK 16
#define LDP 132   // k-major LDS leading pad: 128+4 keeps float4 alignment, <=2-way conflicts

__global__ __launch_bounds__(256) void dist_k(const float* __restrict__ x,
                                              const float* __restrict__ embed,
                                              const float* __restrict__ norm2,
                                              unsigned long long* __restrict__ best) {
    __shared__ float As[BK][LDP];   // As[c][r] = x[rBase+r][d0+c]
    __shared__ float Bs[BK][LDP];   // Bs[c][r] = embed[cBase+r][d0+c]

    const int tid = threadIdx.x;
    const int tx = tid & 15;        // code group (8 codes)
    const int ty = tid >> 4;        // row group (8 rows)
    const int rBase = blockIdx.y * BM;
    const int cBase = blockIdx.x * BN;

    float acc[8][8];
    #pragma unroll
    for (int i = 0; i < 8; ++i)
        #pragma unroll
        for (int j = 0; j < 8; ++j) acc[i][j] = 0.f;

    const int ar  = tid >> 1;        // 0..127
    const int ac0 = (tid & 1) * 8;   // 0 or 8
    const float* xA = x     + (size_t)(rBase + ar) * DIM + ac0;
    const float* eB = embed + (size_t)(cBase + ar) * DIM + ac0;

    for (int d0 = 0; d0 < DIM; d0 += BK) {
        float4 av0 = *(const float4*)(xA + d0);
        float4 av1 = *(const float4*)(xA + d0 + 4);
        float4 bv0 = *(const float4*)(eB + d0);
        float4 bv1 = *(const float4*)(eB + d0 + 4);
        __syncthreads();   // previous iteration's readers done before overwrite
        As[ac0 + 0][ar] = av0.x; As[ac0 + 1][ar] = av0.y;
        As[ac0 + 2][ar] = av0.z; As[ac0 + 3][ar] = av0.w;
        As[ac0 + 4][ar] = av1.x; As[ac0 + 5][ar] = av1.y;
        As[ac0 + 6][ar] = av1.z; As[ac0 + 7][ar] = av1.w;
        Bs[ac0 + 0][ar] = bv0.x; Bs[ac0 + 1][ar] = bv0.y;
        Bs[ac0 + 2][ar] = bv0.z; Bs[ac0 + 3][ar] = bv0.w;
        Bs[ac0 + 4][ar] = bv1.x; Bs[ac0 + 5][ar] = bv1.y;
        Bs[ac0 + 6][ar] = bv1.z; Bs[ac0 + 7][ar] = bv1.w;
        __syncthreads();
        #pragma unroll
        for (int kk = 0; kk < BK; ++kk) {
            float4 a0 = *(const float4*)&As[kk][ty * 8];
            float4 a1 = *(const float4*)&As[kk][ty * 8 + 4];
            float4 b0 = *(const float4*)&Bs[kk][tx * 8];
            float4 b1 = *(const float4*)&Bs[kk][tx * 8 + 4];
            float a[8] = {a0.x, a0.y, a0.z, a0.w, a1.x, a1.y, a1.z, a1.w};
            float b[8] = {b0.x, b0.y, b0.z, b0.w, b1.x, b1.y, b1.z, b1.w};
            #pragma unroll
            for (int i = 0; i < 8; ++i)
                #pragma unroll
                for (int j = 0; j < 8; ++j)
                    acc[i][j] = fmaf(a[i], b[j], acc[i][j]);
        }
    }

    // Epilogue: dist = 2*acc - ||e||^2 (the -||x||^2 row-constant can't change argmax)
    float n2v[8];
    #pragma unroll
    for (int j = 0; j < 8; ++j) n2v[j] = norm2[cBase + tx * 8 + j];

    #pragma unroll
    for (int i = 0; i < 8; ++i) {
        float bval = -3.4e38f;
        int   bidx = 0;
        #pragma unroll
        for (int j = 0; j < 8; ++j) {
            float v = 2.f * acc[i][j] - n2v[j];
            int ii = cBase + tx * 8 + j;
            if (v > bval) { bval = v; bidx = ii; }   // strict > keeps smallest idx
        }
        // reduce across the 16 tx-lanes of this row (contiguous within a wave)
        #pragma unroll
        for (int off = 1; off < 16; off <<= 1) {
            float ov = __shfl_xor(bval, off);
            int   oi = __shfl_xor(bidx, off);
            if (ov > bval || (ov == bval && oi < bidx)) { bval = ov; bidx = oi; }
        }
        if (tx == 0) {
            unsigned long long key =
                ((unsigned long long)enc_f(bval) << 32) | (unsigned int)(~(unsigned int)bidx);
            atomicMax(best + rBase + ty * 8 + i, key);
        }
    }
}

// ---- K2: per-row gather (quantize) + scatter (counts, embed_sum) ----
__global__ void assign_k(const float* __restrict__ x,
                         const float* __restrict__ embed,
                         const unsigned long long* __restrict__ best,
                         float* __restrict__ out) {
    int row  = blockIdx.x;
    int lane = threadIdx.x;   // 64
    int idx  = (int)(~(unsigned int)best[row]);
    if (lane == 0) {
        out[OUT_IND + row] = (float)idx;
        atomicAdd(&out[OUT_CSN + idx], OMDF);
    }
    const float4* e  = (const float4*)(embed + (size_t)idx * DIM);
    const float4* xr = (const float4*)(x + (size_t)row * DIM);
    float4* q = (float4*)(out + OUT_QUANT + (size_t)row * DIM);
    float* avg = out + OUT_AVG + (size_t)idx * DIM;
    #pragma unroll
    for (int j = lane; j < DIM / 4; j += 64) {
        q[j] = e[j];
        float4 xv = xr[j];
        atomicAdd(&avg[j * 4 + 0], OMDF * xv.x);
        atomicAdd(&avg[j * 4 + 1], OMDF * xv.y);
        atomicAdd(&avg[j * 4 + 2], OMDF * xv.z);
        atomicAdd(&avg[j * 4 + 3], OMDF * xv.w);
    }
}

// ---- K3: S = sum(cluster_size_new), single block ----
__global__ void sum_k(const float* __restrict__ out, float* __restrict__ S) {
    __shared__ float red[4];
    float s = 0.f;
    for (int i = threadIdx.x; i < KCODES; i += 256) s += out[OUT_CSN + i];
    #pragma unroll
    for (int off = 32; off; off >>= 1) s += __shfl_down(s, off);
    if ((threadIdx.x & 63) == 0) red[threadIdx.x >> 6] = s;
    __syncthreads();
    if (threadIdx.x == 0) S[0] = red[0] + red[1] + red[2] + red[3];
}

// ---- K3b: inv_cs[k] = (S + K*eps) / ((csn+eps) * S) ----
__global__ void inv_k(const float* __restrict__ out, const float* __restrict__ S,
                      float* __restrict__ inv_cs) {
    int k = blockIdx.x * 256 + threadIdx.x;
    if (k >= KCODES) return;
    float Sv = S[0];
    inv_cs[k] = (Sv + (float)KCODES * EPSF) / ((out[OUT_CSN + k] + EPSF) * Sv);
}

// ---- K4: embed_normalized = embed_avg_new * inv_cs[k] ----
__global__ void normout_k(float* __restrict__ out, const float* __restrict__ inv_cs) {
    int i = blockIdx.x * 256 + threadIdx.x;       // float4 index, < 1048576
    const float4* avg = (const float4*)(out + OUT_AVG);
    float4* nrm = (float4*)(out + OUT_NORM);
    float inv = inv_cs[i >> 7];                   // (i*4) >> 9
    float4 v = avg[i];
    v.x *= inv; v.y *= inv; v.z *= inv; v.w *= inv;
    nrm[i] = v;
}

extern "C" void kernel_launch(void* const* d_in, const int* in_sizes, int n_in,
                              void* d_out, int out_size, void* d_ws, size_t ws_size,
                              hipStream_t stream) {
    const float* x     = (const float*)d_in[0];
    const float* embed = (const float*)d_in[1];
    const float* cs    = (const float*)d_in[2];
    const float* eavg  = (const float*)d_in[3];
    float* out = (float*)d_out;

    unsigned long long* best = (unsigned long long*)d_ws;
    float* norm2  = (float*)((char*)d_ws + 262144);
    float* Ssum   = (float*)((char*)d_ws + 262144 + 32768);
    float* inv_cs = Ssum + 1;

    init_k<<<2048, 256, 0, stream>>>(cs, eavg, out, best);
    norms_k<<<(KCODES * 64) / 256, 256, 0, stream>>>(embed, norm2);
    dist_k<<<dim3(KCODES / BN, N_ROWS / BM), 256, 0, stream>>>(x, embed, norm2, best);
    assign_k<<<N_ROWS, 64, 0, stream>>>(x, embed, best, out);
    sum_k<<<1, 256, 0, stream>>>(out, Ssum);
    inv_k<<<KCODES / 256, 256, 0, stream>>>(out, Ssum, inv_cs);
    normout_k<<<(KCODES * DIM / 4) / 256, 256, 0, stream>>>(out, inv_cs);
}

// Round 2
// 1858.672 us; speedup vs baseline: 1.7562x; 1.7562x over previous
//
#include <hip/hip_runtime.h>
#include <stdint.h>

// Problem constants
#define N_ROWS 32768
#define KCODES 8192
#define DIM    512
#define DECAYF 0.8f
#define EPSF   1e-5f

// d_out layout (float32, reference return order)
#define OUT_QUANT 0
#define OUT_IND   (N_ROWS * DIM)                 // 16777216
#define OUT_CSN   (OUT_IND + N_ROWS)             // 16809984
#define OUT_AVG   (OUT_CSN + KCODES)             // 16818176
#define OUT_NORM  (OUT_AVG + KCODES * DIM)       // 21012480

// During dist_k, d_out regions are scratch for the X bf16 planes:
//   quant region: Xh (32 MiB) + Xm (32 MiB);  avg+norm regions: Xl (32 MiB).
// They are overwritten afterwards by init2/assign/normout in that order.
// ws layout: [0,256K) best u64; [256K,288K) norm2; [288K] S; [+4] inv_cs;
//            [1MiB..) Eh, Em, El planes (8 MiB each).  Requires ws >= 26 MiB.

typedef __attribute__((ext_vector_type(8))) short short8v;
typedef __attribute__((ext_vector_type(4))) float f32x4;

__device__ __forceinline__ unsigned int enc_f(float v) {
    unsigned int b = __float_as_uint(v);
    return (b & 0x80000000u) ? ~b : (b | 0x80000000u);
}

__device__ __forceinline__ void gl16(const ushort* g, const char* lds) {
    __builtin_amdgcn_global_load_lds(
        (const __attribute__((address_space(1))) unsigned int*)g,
        (__attribute__((address_space(3))) unsigned int*)lds, 16, 0, 0);
}

// ---- split fp32 -> 3 bf16 planes (h + m + l, round-to-nearest each) ----
__global__ void cvt_k(const float* __restrict__ src, ushort* __restrict__ ph,
                      ushort* __restrict__ pm, ushort* __restrict__ pl, int n8) {
    int i = blockIdx.x * 256 + threadIdx.x;
    if (i >= n8) return;
    const float4* s4 = (const float4*)src;
    float4 v0 = s4[(size_t)i * 2], v1 = s4[(size_t)i * 2 + 1];
    float f[8] = {v0.x, v0.y, v0.z, v0.w, v1.x, v1.y, v1.z, v1.w};
    short8v hv, mv, lv;
    #pragma unroll
    for (int j = 0; j < 8; ++j) {
        unsigned u = __float_as_uint(f[j]);
        unsigned hr = (u + 0x7fffu + ((u >> 16) & 1u)) >> 16;
        float r1 = f[j] - __uint_as_float(hr << 16);
        unsigned um = __float_as_uint(r1);
        unsigned mr = (um + 0x7fffu + ((um >> 16) & 1u)) >> 16;
        float r2 = r1 - __uint_as_float(mr << 16);
        unsigned ul = __float_as_uint(r2);
        unsigned lr = (ul + 0x7fffu + ((ul >> 16) & 1u)) >> 16;
        hv[j] = (short)hr; mv[j] = (short)mr; lv[j] = (short)lr;
    }
    *(short8v*)(ph + (size_t)i * 8) = hv;
    *(short8v*)(pm + (size_t)i * 8) = mv;
    *(short8v*)(pl + (size_t)i * 8) = lv;
}

__global__ void binit_k(unsigned long long* __restrict__ best) {
    int i = blockIdx.x * 256 + threadIdx.x;
    if (i < N_ROWS) best[i] = 0ull;
}

// ---- per-code squared norm (fp32 source, same as R1) ----
__global__ void norms_k(const float* __restrict__ embed, float* __restrict__ norm2) {
    int gt = blockIdx.x * blockDim.x + threadIdx.x;
    int wave = gt >> 6, lane = threadIdx.x & 63;
    if (wave >= KCODES) return;
    const float4* row = (const float4*)(embed + (size_t)wave * DIM);
    float s = 0.f;
    #pragma unroll
    for (int j = 0; j < 2; ++j) {
        float4 v = row[lane * 2 + j];
        s += v.x * v.x + v.y * v.y + v.z * v.z + v.w * v.w;
    }
    #pragma unroll
    for (int off = 32; off; off >>= 1) s += __shfl_down(s, off);
    if (lane == 0) norm2[wave] = s;
}

// ---- K1: split-bf16 MFMA distance GEMM + fused argmax ----
#define BM 128
#define BN 128
#define BK 32
#define TILEB 8192    // bytes per plane tile: 128 rows x 32 bf16

__global__ __launch_bounds__(256, 2) void dist_k(
    const ushort* __restrict__ Xh, const ushort* __restrict__ Xm, const ushort* __restrict__ Xl,
    const ushort* __restrict__ Eh, const ushort* __restrict__ Em, const ushort* __restrict__ El,
    const float* __restrict__ norm2, unsigned long long* __restrict__ best)
{
    __shared__ ushort smem[6 * 4096];   // Ah Am Al Bh Bm Bl, 8 KiB each (48 KiB)
    char* sb = (char*)smem;

    const int tid = threadIdx.x;
    const int w = tid >> 6, l = tid & 63;

    // XCD-aware swizzle (16384 % 8 == 0 -> simple form is bijective)
    int b = blockIdx.x;
    int swz = ((b & 7) << 11) | (b >> 3);
    const int by = swz >> 6, bx = swz & 63;       // 256 row-tiles x 64 col-tiles
    const int rBase = by * BM, cBase = bx * BN;

    // --- staging geometry: 2 rounds/tile, linear LDS dest, pre-swizzled source ---
    // linear byte o in tile: row = o>>6, kb = (o>>4)&3 ; swizzle s(row) = (row>>1)&3
    int o0 = (w << 10) | (l << 4);
    int o1 = o0 + 4096;
    int row0 = o0 >> 6, kb0 = (o0 >> 4) & 3;
    int row1 = o1 >> 6, kb1 = (o1 >> 4) & 3;
    int c0 = (kb0 ^ ((row0 >> 1) & 3)) << 3;      // element offset within BK
    int c1 = (kb1 ^ ((row1 >> 1) & 3)) << 3;
    size_t offA0 = (size_t)(rBase + row0) * DIM + c0;
    size_t offA1 = (size_t)(rBase + row1) * DIM + c1;
    size_t offB0 = (size_t)(cBase + row0) * DIM + c0;
    size_t offB1 = (size_t)(cBase + row1) * DIM + c1;
    const char* ldsw0 = sb + (w << 10);           // wave-uniform dest, round 0
    const char* ldsw1 = sb + 4096 + (w << 10);    // round 1

    const int wr = w >> 1, wc = w & 1;            // 2x2 wave grid, 64x64 each
    const int ln = l & 15, kq = l >> 4;

    f32x4 acc[4][4];
    #pragma unroll
    for (int i = 0; i < 4; ++i)
        #pragma unroll
        for (int j = 0; j < 4; ++j) acc[i][j] = (f32x4){0.f, 0.f, 0.f, 0.f};

    for (int d0 = 0; d0 < DIM; d0 += BK) {
        __syncthreads();   // previous iteration's LDS readers done
        gl16(Xh + offA0 + d0, ldsw0 + 0 * TILEB);
        gl16(Xh + offA1 + d0, ldsw1 + 0 * TILEB);
        gl16(Xm + offA0 + d0, ldsw0 + 1 * TILEB);
        gl16(Xm + offA1 + d0, ldsw1 + 1 * TILEB);
        gl16(Xl + offA0 + d0, ldsw0 + 2 * TILEB);
        gl16(Xl + offA1 + d0, ldsw1 + 2 * TILEB);
        gl16(Eh + offB0 + d0, ldsw0 + 3 * TILEB);
        gl16(Eh + offB1 + d0, ldsw1 + 3 * TILEB);
        gl16(Em + offB0 + d0, ldsw0 + 4 * TILEB);
        gl16(Em + offB1 + d0, ldsw1 + 4 * TILEB);
        gl16(El + offB0 + d0, ldsw0 + 5 * TILEB);
        gl16(El + offB1 + d0, ldsw1 + 5 * TILEB);
        __syncthreads();   // vmcnt(0) drain + all waves' staging visible

        short8v ah[4], am[4], av[4];
        #pragma unroll
        for (int ai = 0; ai < 4; ++ai) {
            int rr = wr * 64 + ai * 16 + ln;
            int ba = rr * 64 + ((kq ^ ((rr >> 1) & 3)) << 4);
            ah[ai] = *(const short8v*)(sb + 0 * TILEB + ba);
            am[ai] = *(const short8v*)(sb + 1 * TILEB + ba);
            av[ai] = *(const short8v*)(sb + 2 * TILEB + ba);
        }
        #pragma unroll
        for (int bj = 0; bj < 4; ++bj) {
            int rr = wc * 64 + bj * 16 + ln;
            int bb = rr * 64 + ((kq ^ ((rr >> 1) & 3)) << 4);
            short8v bh = *(const short8v*)(sb + 3 * TILEB + bb);
            short8v bm = *(const short8v*)(sb + 4 * TILEB + bb);
            short8v bl = *(const short8v*)(sb + 5 * TILEB + bb);
            #pragma unroll
            for (int ai = 0; ai < 4; ++ai) {
                f32x4 a = acc[ai][bj];
                a = __builtin_amdgcn_mfma_f32_16x16x32_bf16(ah[ai], bh, a, 0, 0, 0);
                a = __builtin_amdgcn_mfma_f32_16x16x32_bf16(ah[ai], bm, a, 0, 0, 0);
                a = __builtin_amdgcn_mfma_f32_16x16x32_bf16(am[ai], bh, a, 0, 0, 0);
                a = __builtin_amdgcn_mfma_f32_16x16x32_bf16(am[ai], bm, a, 0, 0, 0);
                a = __builtin_amdgcn_mfma_f32_16x16x32_bf16(ah[ai], bl, a, 0, 0, 0);
                a = __builtin_amdgcn_mfma_f32_16x16x32_bf16(av[ai], bh, a, 0, 0, 0);
                acc[ai][bj] = a;
            }
        }
    }

    // ---- epilogue: dist = 2*dot - ||e||^2 ; per-row argmax via packed atomicMax ----
    float n2v[4];
    #pragma unroll
    for (int bj = 0; bj < 4; ++bj)
        n2v[bj] = norm2[cBase + wc * 64 + bj * 16 + ln];

    #pragma unroll
    for (int ai = 0; ai < 4; ++ai) {
        #pragma unroll
        for (int r = 0; r < 4; ++r) {
            float bval = -3.4e38f;
            int bidx = 0;
            #pragma unroll
            for (int bj = 0; bj < 4; ++bj) {
                float v = 2.f * acc[ai][bj][r] - n2v[bj];
                if (v > bval) { bval = v; bidx = cBase + wc * 64 + bj * 16 + ln; }
            }
            #pragma unroll
            for (int off = 1; off < 16; off <<= 1) {
                float ov = __shfl_xor(bval, off);
                int   oi = __shfl_xor(bidx, off);
                if (ov > bval || (ov == bval && oi < bidx)) { bval = ov; bidx = oi; }
            }
            if (ln == 0) {
                unsigned long long key =
                    ((unsigned long long)enc_f(bval) << 32) | (unsigned int)(~(unsigned int)bidx);
                atomicMax(&best[rBase + wr * 64 + ai * 16 + kq * 4 + r], key);
            }
        }
    }
}

// ---- post-dist init: csn = 0.8*cs ; avg = 0.8*eavg (overwrites Xl scratch) ----
__global__ void init2_k(const float* __restrict__ cs, const float* __restrict__ eavg,
                        float* __restrict__ out) {
    int i = blockIdx.x * blockDim.x + threadIdx.x;
    int stride = gridDim.x * blockDim.x;
    for (int idx = i; idx < KCODES * DIM; idx += stride) {
        out[OUT_AVG + idx] = DECAYF * eavg[idx];
        if (idx < KCODES) out[OUT_CSN + idx] = DECAYF * cs[idx];
    }
}

// ---- gather quantize + scatter counts/embed_sum ----
__global__ void assign_k(const float* __restrict__ x, const float* __restrict__ embed,
                         const unsigned long long* __restrict__ best, float* __restrict__ out) {
    int row = blockIdx.x, lane = threadIdx.x;
    int idx = (int)(~(unsigned int)best[row]);
    if (lane == 0) {
        out[OUT_IND + row] = (float)idx;
        atomicAdd(&out[OUT_CSN + idx], 0.2f);
    }
    const float4* e  = (const float4*)(embed + (size_t)idx * DIM);
    const float4* xr = (const float4*)(x + (size_t)row * DIM);
    float4* q = (float4*)(out + OUT_QUANT + (size_t)row * DIM);
    float* avg = out + OUT_AVG + (size_t)idx * DIM;
    #pragma unroll
    for (int j = lane; j < DIM / 4; j += 64) {
        q[j] = e[j];
        float4 xv = xr[j];
        atomicAdd(&avg[j * 4 + 0], 0.2f * xv.x);
        atomicAdd(&avg[j * 4 + 1], 0.2f * xv.y);
        atomicAdd(&avg[j * 4 + 2], 0.2f * xv.z);
        atomicAdd(&avg[j * 4 + 3], 0.2f * xv.w);
    }
}

__global__ void sum_k(const float* __restrict__ out, float* __restrict__ S) {
    __shared__ float red[4];
    float s = 0.f;
    for (int i = threadIdx.x; i < KCODES; i += 256) s += out[OUT_CSN + i];
    #pragma unroll
    for (int off = 32; off; off >>= 1) s += __shfl_down(s, off);
    if ((threadIdx.x & 63) == 0) red[threadIdx.x >> 6] = s;
    __syncthreads();
    if (threadIdx.x == 0) S[0] = red[0] + red[1] + red[2] + red[3];
}

__global__ void inv_k(const float* __restrict__ out, const float* __restrict__ S,
                      float* __restrict__ inv_cs) {
    int k = blockIdx.x * 256 + threadIdx.x;
    if (k >= KCODES) return;
    float Sv = S[0];
    inv_cs[k] = (Sv + (float)KCODES * EPSF) / ((out[OUT_CSN + k] + EPSF) * Sv);
}

__global__ void normout_k(float* __restrict__ out, const float* __restrict__ inv_cs) {
    int i = blockIdx.x * 256 + threadIdx.x;
    const float4* avg = (const float4*)(out + OUT_AVG);
    float4* nrm = (float4*)(out + OUT_NORM);
    float inv = inv_cs[i >> 7];
    float4 v = avg[i];
    v.x *= inv; v.y *= inv; v.z *= inv; v.w *= inv;
    nrm[i] = v;
}

extern "C" void kernel_launch(void* const* d_in, const int* in_sizes, int n_in,
                              void* d_out, int out_size, void* d_ws, size_t ws_size,
                              hipStream_t stream) {
    const float* x     = (const float*)d_in[0];
    const float* embed = (const float*)d_in[1];
    const float* cs    = (const float*)d_in[2];
    const float* eavg  = (const float*)d_in[3];
    float* out = (float*)d_out;
    char*  w   = (char*)d_ws;

    unsigned long long* best = (unsigned long long*)w;
    float* norm2  = (float*)(w + 262144);
    float* Ssum   = (float*)(w + 294912);
    float* inv_cs = Ssum + 1;
    ushort* Eh = (ushort*)(w + (1u << 20));
    ushort* Em = Eh + (size_t)KCODES * DIM;
    ushort* El = Em + (size_t)KCODES * DIM;

    // X planes in d_out scratch regions (dead until overwritten post-dist)
    ushort* Xh = (ushort*)out;                          // quant region, 1st half
    ushort* Xm = Xh + (size_t)N_ROWS * DIM;             // quant region, 2nd half
    ushort* Xl = (ushort*)(out + OUT_AVG);              // avg+norm regions

    binit_k<<<N_ROWS / 256, 256, 0, stream>>>(best);
    cvt_k<<<(N_ROWS * DIM / 8) / 256, 256, 0, stream>>>(x, Xh, Xm, Xl, N_ROWS * DIM / 8);
    cvt_k<<<(KCODES * DIM / 8) / 256, 256, 0, stream>>>(embed, Eh, Em, El, KCODES * DIM / 8);
    norms_k<<<(KCODES * 64) / 256, 256, 0, stream>>>(embed, norm2);
    dist_k<<<(N_ROWS / BM) * (KCODES / BN), 256, 0, stream>>>(Xh, Xm, Xl, Eh, Em, El, norm2, best);
    init2_k<<<2048, 256, 0, stream>>>(cs, eavg, out);
    assign_k<<<N_ROWS, 64, 0, stream>>>(x, embed, best, out);
    sum_k<<<1, 256, 0, stream>>>(out, Ssum);
    inv_k<<<KCODES / 256, 256, 0, stream>>>(out, Ssum, inv_cs);
    normout_k<<<(KCODES * DIM / 4) / 256, 256, 0, stream>>>(out, inv_cs);
}

// Round 3
// 1132.200 us; speedup vs baseline: 2.8830x; 1.6416x over previous
//
#include <hip/hip_runtime.h>
#include <stdint.h>

// Problem constants
#define N_ROWS 32768
#define KCODES 8192
#define DIM    512
#define DECAYF 0.8f
#define EPSF   1e-5f

// d_out layout (float32, reference return order)
#define OUT_QUANT 0
#define OUT_IND   (N_ROWS * DIM)                 // 16777216
#define OUT_CSN   (OUT_IND + N_ROWS)             // 16809984
#define OUT_AVG   (OUT_CSN + KCODES)             // 16818176
#define OUT_NORM  (OUT_AVG + KCODES * DIM)       // 21012480

// During dist_k the quant region (64 MiB) holds the X f16 planes (Xh 32 MiB + Xm 32 MiB);
// it is overwritten by assign_k afterwards.
// ws: [0,256K) best u64; [256K,288K) norm2; [288K] S; [+4] inv_cs; [1MiB..) Eh, Em (8 MiB each).

typedef _Float16 f16x8 __attribute__((ext_vector_type(8)));
typedef __attribute__((ext_vector_type(4))) float f32x4;

__device__ __forceinline__ unsigned int enc_f(float v) {
    unsigned int b = __float_as_uint(v);
    return (b & 0x80000000u) ? ~b : (b | 0x80000000u);
}

__device__ __forceinline__ void gl16(const _Float16* g, const char* lds) {
    __builtin_amdgcn_global_load_lds(
        (const __attribute__((address_space(1))) unsigned int*)g,
        (__attribute__((address_space(3))) unsigned int*)lds, 16, 0, 0);
}

// ---- split fp32 -> f16 planes: h = f16(v), m' = f16((v-h)*1024) ----
__global__ void cvt_k(const float* __restrict__ src, _Float16* __restrict__ ph,
                      _Float16* __restrict__ pm, int n8) {
    int i = blockIdx.x * 256 + threadIdx.x;
    if (i >= n8) return;
    const float4* s4 = (const float4*)src;
    float4 v0 = s4[(size_t)i * 2], v1 = s4[(size_t)i * 2 + 1];
    float f[8] = {v0.x, v0.y, v0.z, v0.w, v1.x, v1.y, v1.z, v1.w};
    f16x8 hv, mv;
    #pragma unroll
    for (int j = 0; j < 8; ++j) {
        _Float16 h = (_Float16)f[j];
        float r = f[j] - (float)h;
        hv[j] = h;
        mv[j] = (_Float16)(r * 1024.0f);
    }
    *(f16x8*)(ph + (size_t)i * 8) = hv;
    *(f16x8*)(pm + (size_t)i * 8) = mv;
}

__global__ void binit_k(unsigned long long* __restrict__ best) {
    int i = blockIdx.x * 256 + threadIdx.x;
    if (i < N_ROWS) best[i] = 0ull;
}

// ---- per-code squared norm (fp32 source) ----
__global__ void norms_k(const float* __restrict__ embed, float* __restrict__ norm2) {
    int gt = blockIdx.x * blockDim.x + threadIdx.x;
    int wave = gt >> 6, lane = threadIdx.x & 63;
    if (wave >= KCODES) return;
    const float4* row = (const float4*)(embed + (size_t)wave * DIM);
    float s = 0.f;
    #pragma unroll
    for (int j = 0; j < 2; ++j) {
        float4 v = row[lane * 2 + j];
        s += v.x * v.x + v.y * v.y + v.z * v.z + v.w * v.w;
    }
    #pragma unroll
    for (int off = 32; off; off >>= 1) s += __shfl_down(s, off);
    if (lane == 0) norm2[wave] = s;
}

// ---- K1: f16 2-plane (3-pass) MFMA distance GEMM + fused argmax ----
#define BM 128
#define BN 128
#define BK 32
#define TILEB 8192    // bytes per plane tile: 128 rows x 32 f16

__global__ __launch_bounds__(256, 4) void dist_k(
    const _Float16* __restrict__ Xh, const _Float16* __restrict__ Xm,
    const _Float16* __restrict__ Eh, const _Float16* __restrict__ Em,
    const float* __restrict__ norm2, unsigned long long* __restrict__ best)
{
    __shared__ _Float16 smem[4 * 4096];   // Ah Am Bh Bm, 8 KiB each (32 KiB)
    char* sb = (char*)smem;

    const int tid = threadIdx.x;
    const int w = tid >> 6, l = tid & 63;

    // XCD column-band mapping: XCD (b&7) owns 8 consecutive bx; bx-minor, by-major.
    int b = blockIdx.x;
    int xcd = b & 7;
    int local = b >> 3;            // 0..2047
    int bxl = local & 7;
    int by = local >> 3;           // 0..255
    int bx = xcd * 8 + bxl;        // 0..63
    const int rBase = by * BM, cBase = bx * BN;

    // staging: 2 rounds/tile, linear LDS dest, pre-swizzled source
    int o0 = (w << 10) | (l << 4);
    int o1 = o0 + 4096;
    int row0 = o0 >> 6, kb0 = (o0 >> 4) & 3;
    int row1 = o1 >> 6, kb1 = (o1 >> 4) & 3;
    int c0 = (kb0 ^ ((row0 >> 1) & 3)) << 3;
    int c1 = (kb1 ^ ((row1 >> 1) & 3)) << 3;
    unsigned offA0 = (unsigned)(rBase + row0) * DIM + c0;
    unsigned offA1 = (unsigned)(rBase + row1) * DIM + c1;
    unsigned offB0 = (unsigned)(cBase + row0) * DIM + c0;
    unsigned offB1 = (unsigned)(cBase + row1) * DIM + c1;
    const char* ldsw0 = sb + (w << 10);
    const char* ldsw1 = sb + 4096 + (w << 10);

    const int wr = w >> 1, wc = w & 1;     // 2x2 wave grid, 64x64 each
    const int ln = l & 15, kq = l >> 4;

    f32x4 acc[4][4];
    #pragma unroll
    for (int i = 0; i < 4; ++i)
        #pragma unroll
        for (int j = 0; j < 4; ++j) acc[i][j] = (f32x4){0.f, 0.f, 0.f, 0.f};

    // ds_read bases: the XOR swizzle term is invariant in ai/bj (ai*16>>1 = 8*ai, 8*ai & 3 == 0)
    const int rrA0 = wr * 64 + ln;
    const int rrB0 = wc * 64 + ln;
    const int baA = rrA0 * 64 + ((kq ^ ((rrA0 >> 1) & 3)) << 4);
    const int baB = rrB0 * 64 + ((kq ^ ((rrB0 >> 1) & 3)) << 4);
    const _Float16 S = (_Float16)0.0009765625f;   // 2^-10, exact

    for (int d0 = 0; d0 < DIM; d0 += BK) {
        __syncthreads();
        gl16(Xh + offA0 + d0, ldsw0 + 0 * TILEB);
        gl16(Xh + offA1 + d0, ldsw1 + 0 * TILEB);
        gl16(Xm + offA0 + d0, ldsw0 + 1 * TILEB);
        gl16(Xm + offA1 + d0, ldsw1 + 1 * TILEB);
        gl16(Eh + offB0 + d0, ldsw0 + 2 * TILEB);
        gl16(Eh + offB1 + d0, ldsw1 + 2 * TILEB);
        gl16(Em + offB0 + d0, ldsw0 + 3 * TILEB);
        gl16(Em + offB1 + d0, ldsw1 + 3 * TILEB);
        __syncthreads();

        f16x8 ah[4], bh[4], t[4];
        #pragma unroll
        for (int ai = 0; ai < 4; ++ai)
            ah[ai] = *(const f16x8*)(sb + 0 * TILEB + baA + ai * 1024);
        #pragma unroll
        for (int bj = 0; bj < 4; ++bj)
            bh[bj] = *(const f16x8*)(sb + 2 * TILEB + baB + bj * 1024);

        // pass 1: h_a * h_b
        #pragma unroll
        for (int bj = 0; bj < 4; ++bj)
            #pragma unroll
            for (int ai = 0; ai < 4; ++ai)
                acc[ai][bj] = __builtin_amdgcn_mfma_f32_16x16x32_f16(ah[ai], bh[bj], acc[ai][bj], 0, 0, 0);

        // pass 2: (h_a * 2^-10) * (m_b * 2^10) = h_a * m_b
        #pragma unroll
        for (int ai = 0; ai < 4; ++ai) ah[ai] *= S;
        #pragma unroll
        for (int bj = 0; bj < 4; ++bj)
            t[bj] = *(const f16x8*)(sb + 3 * TILEB + baB + bj * 1024);
        #pragma unroll
        for (int bj = 0; bj < 4; ++bj)
            #pragma unroll
            for (int ai = 0; ai < 4; ++ai)
                acc[ai][bj] = __builtin_amdgcn_mfma_f32_16x16x32_f16(ah[ai], t[bj], acc[ai][bj], 0, 0, 0);

        // pass 3: (m_a * 2^10) * (h_b * 2^-10) = m_a * h_b
        #pragma unroll
        for (int bj = 0; bj < 4; ++bj) bh[bj] *= S;
        #pragma unroll
        for (int ai = 0; ai < 4; ++ai)
            t[ai] = *(const f16x8*)(sb + 1 * TILEB + baA + ai * 1024);
        #pragma unroll
        for (int bj = 0; bj < 4; ++bj)
            #pragma unroll
            for (int ai = 0; ai < 4; ++ai)
                acc[ai][bj] = __builtin_amdgcn_mfma_f32_16x16x32_f16(t[ai], bh[bj], acc[ai][bj], 0, 0, 0);
    }

    // ---- epilogue: dist = 2*dot - ||e||^2 ; per-row argmax via packed atomicMax ----
    float n2v[4];
    #pragma unroll
    for (int bj = 0; bj < 4; ++bj)
        n2v[bj] = norm2[cBase + wc * 64 + bj * 16 + ln];

    #pragma unroll
    for (int ai = 0; ai < 4; ++ai) {
        #pragma unroll
        for (int r = 0; r < 4; ++r) {
            float bval = -3.4e38f;
            int bidx = 0;
            #pragma unroll
            for (int bj = 0; bj < 4; ++bj) {
                float v = 2.f * acc[ai][bj][r] - n2v[bj];
                if (v > bval) { bval = v; bidx = cBase + wc * 64 + bj * 16 + ln; }
            }
            #pragma unroll
            for (int off = 1; off < 16; off <<= 1) {
                float ov = __shfl_xor(bval, off);
                int   oi = __shfl_xor(bidx, off);
                if (ov > bval || (ov == bval && oi < bidx)) { bval = ov; bidx = oi; }
            }
            if (ln == 0) {
                unsigned long long key =
                    ((unsigned long long)enc_f(bval) << 32) | (unsigned int)(~(unsigned int)bidx);
                atomicMax(&best[rBase + wr * 64 + ai * 16 + kq * 4 + r], key);
            }
        }
    }
}

// ---- post-dist init: csn = 0.8*cs ; avg = 0.8*eavg ----
__global__ void init2_k(const float* __restrict__ cs, const float* __restrict__ eavg,
                        float* __restrict__ out) {
    int i = blockIdx.x * blockDim.x + threadIdx.x;
    int stride = gridDim.x * blockDim.x;
    for (int idx = i; idx < KCODES * DIM; idx += stride) {
        out[OUT_AVG + idx] = DECAYF * eavg[idx];
        if (idx < KCODES) out[OUT_CSN + idx] = DECAYF * cs[idx];
    }
}

// ---- gather quantize + scatter counts/embed_sum ----
__global__ void assign_k(const float* __restrict__ x, const float* __restrict__ embed,
                         const unsigned long long* __restrict__ best, float* __restrict__ out) {
    int row = blockIdx.x, lane = threadIdx.x;
    int idx = (int)(~(unsigned int)best[row]);
    if (lane == 0) {
        out[OUT_IND + row] = (float)idx;
        atomicAdd(&out[OUT_CSN + idx], 0.2f);
    }
    const float4* e  = (const float4*)(embed + (size_t)idx * DIM);
    const float4* xr = (const float4*)(x + (size_t)row * DIM);
    float4* q = (float4*)(out + OUT_QUANT + (size_t)row * DIM);
    float* avg = out + OUT_AVG + (size_t)idx * DIM;
    #pragma unroll
    for (int j = lane; j < DIM / 4; j += 64) {
        q[j] = e[j];
        float4 xv = xr[j];
        atomicAdd(&avg[j * 4 + 0], 0.2f * xv.x);
        atomicAdd(&avg[j * 4 + 1], 0.2f * xv.y);
        atomicAdd(&avg[j * 4 + 2], 0.2f * xv.z);
        atomicAdd(&avg[j * 4 + 3], 0.2f * xv.w);
    }
}

__global__ void sum_k(const float* __restrict__ out, float* __restrict__ S) {
    __shared__ float red[4];
    float s = 0.f;
    for (int i = threadIdx.x; i < KCODES; i += 256) s += out[OUT_CSN + i];
    #pragma unroll
    for (int off = 32; off; off >>= 1) s += __shfl_down(s, off);
    if ((threadIdx.x & 63) == 0) red[threadIdx.x >> 6] = s;
    __syncthreads();
    if (threadIdx.x == 0) S[0] = red[0] + red[1] + red[2] + red[3];
}

__global__ void inv_k(const float* __restrict__ out, const float* __restrict__ S,
                      float* __restrict__ inv_cs) {
    int k = blockIdx.x * 256 + threadIdx.x;
    if (k >= KCODES) return;
    float Sv = S[0];
    inv_cs[k] = (Sv + (float)KCODES * EPSF) / ((out[OUT_CSN + k] + EPSF) * Sv);
}

__global__ void normout_k(float* __restrict__ out, const float* __restrict__ inv_cs) {
    int i = blockIdx.x * 256 + threadIdx.x;
    const float4* avg = (const float4*)(out + OUT_AVG);
    float4* nrm = (float4*)(out + OUT_NORM);
    float inv = inv_cs[i >> 7];
    float4 v = avg[i];
    v.x *= inv; v.y *= inv; v.z *= inv; v.w *= inv;
    nrm[i] = v;
}

extern "C" void kernel_launch(void* const* d_in, const int* in_sizes, int n_in,
                              void* d_out, int out_size, void* d_ws, size_t ws_size,
                              hipStream_t stream) {
    const float* x     = (const float*)d_in[0];
    const float* embed = (const float*)d_in[1];
    const float* cs    = (const float*)d_in[2];
    const float* eavg  = (const float*)d_in[3];
    float* out = (float*)d_out;
    char*  w   = (char*)d_ws;

    unsigned long long* best = (unsigned long long*)w;
    float* norm2  = (float*)(w + 262144);
    float* Ssum   = (float*)(w + 294912);
    float* inv_cs = Ssum + 1;
    _Float16* Eh = (_Float16*)(w + (1u << 20));
    _Float16* Em = Eh + (size_t)KCODES * DIM;

    // X planes exactly fill the quant region (64 MiB), rewritten later by assign_k
    _Float16* Xh = (_Float16*)out;
    _Float16* Xm = Xh + (size_t)N_ROWS * DIM;

    binit_k<<<N_ROWS / 256, 256, 0, stream>>>(best);
    cvt_k<<<(N_ROWS * DIM / 8) / 256, 256, 0, stream>>>(x, Xh, Xm, N_ROWS * DIM / 8);
    cvt_k<<<(KCODES * DIM / 8) / 256, 256, 0, stream>>>(embed, Eh, Em, KCODES * DIM / 8);
    norms_k<<<(KCODES * 64) / 256, 256, 0, stream>>>(embed, norm2);
    dist_k<<<(N_ROWS / BM) * (KCODES / BN), 256, 0, stream>>>(Xh, Xm, Eh, Em, norm2, best);
    init2_k<<<2048, 256, 0, stream>>>(cs, eavg, out);
    assign_k<<<N_ROWS, 64, 0, stream>>>(x, embed, best, out);
    sum_k<<<1, 256, 0, stream>>>(out, Ssum);
    inv_k<<<KCODES / 256, 256, 0, stream>>>(out, Ssum, inv_cs);
    normout_k<<<(KCODES * DIM / 4) / 256, 256, 0, stream>>>(out, inv_cs);
}